// Round 3
// baseline (299.341 us; speedup 1.0000x reference)
//
#include <hip/hip_runtime.h>

typedef unsigned short u16;
typedef __attribute__((ext_vector_type(4))) unsigned int u32x4;
typedef __attribute__((ext_vector_type(4))) float f32x4;
typedef __attribute__((ext_vector_type(8))) __bf16 bf16x8;

// Problem constants (fixed by the reference).
constexpr int BATCH = 2;
constexpr int NV    = 20000;
constexpr int ND    = 8;
constexpr int CH    = 16;
constexpr int NF    = 16;
constexpr int NVD   = NV * ND;        // 160000 rows of y_flat per batch
constexpr int NCHUNK = 36;            // 32 conv chunks + 4 center chunks (K=1152 total)
constexpr int MTOT  = BATCH * NV;     // 40000 GEMM rows
constexpr int BSTR  = 40;             // padded B row stride in bf16 (32+8)

// ws layout (bytes):
//   [0, 10,240,000)              y16  : bf16 [B][NVD][CH]
//   [10,240,000, 10,534,912)     k2c  : bf16 [36][128][32]  (chunk-major weights)
// (zc intermediate ELIMINATED — gather is fused into the GEMM)
constexpr size_t Y16_OFF_B = 0;
constexpr size_t K2C_OFF_B = 10240000;

__device__ __forceinline__ u16 f2bf(float x) {
    unsigned int u = __float_as_uint(x);
    unsigned int r = (u + 0x7fffu + ((u >> 16) & 1u)) >> 16;   // RNE
    return (u16)r;
}
__device__ __forceinline__ unsigned int pack2bf(float a, float b) {
    return (unsigned int)f2bf(a) | ((unsigned int)f2bf(b) << 16);
}

// ---------------- P1: prep — y fp32 -> y16 bf16 table ----------------
// one thread per (b,v,d): reads 16 floats, writes 32 B to y16.
__global__ __launch_bounds__(256) void prep(const float* __restrict__ y,
                                            u16* __restrict__ y16) {
    int tid = blockIdx.x * 256 + threadIdx.x;       // [0, 320000)
    const float4* src = (const float4*)(y + (size_t)tid * 16);
    float4 v0 = src[0], v1 = src[1], v2 = src[2], v3 = src[3];
    u32x4 lo = {pack2bf(v0.x, v0.y), pack2bf(v0.z, v0.w), pack2bf(v1.x, v1.y), pack2bf(v1.z, v1.w)};
    u32x4 hi = {pack2bf(v2.x, v2.y), pack2bf(v2.z, v2.w), pack2bf(v3.x, v3.y), pack2bf(v3.z, v3.w)};
    u16* yd = y16 + (size_t)tid * 16;
    *(u32x4*)(yd)     = lo;
    *(u32x4*)(yd + 8) = hi;
}

// ---------------- P2: build rotated+extended weight matrix K2c ----------------
// K2c[kc][n][kk] = K2[k=kc*32+kk][n=w*16+f];  K2[(r,dd,c),(w,f)] = kernel[r,(dd-w)&7,c,f];
// ext rows (k>=1024, ke=d*16+c): (d==w) ? ck[c,f] : 0
__global__ __launch_bounds__(256) void k2_build(const float* __restrict__ kern,
                                                const float* __restrict__ ck,
                                                u16* __restrict__ k2c) {
    int e = blockIdx.x * 256 + threadIdx.x;   // [0, 36*4096)
    int i = e & 4095;
    int kc = e >> 12;
    int n = i >> 5, kk = i & 31;
    int k = kc * 32 + kk;
    int w = n >> 4, f = n & 15;
    float val;
    if (k < 1024) {
        int r = k >> 7, dd = (k >> 4) & 7, c = k & 15;
        int d = (dd - w) & 7;
        val = kern[((r * 8 + d) * 16 + c) * 16 + f];
    } else {
        int ke = k - 1024;
        int d = ke >> 4, c = ke & 15;
        val = (d == w) ? ck[c * 16 + f] : 0.f;
    }
    k2c[e] = f2bf(val);
}

// ---------------- F: FUSED gather + barycentric + GEMM + bias + relu + max ----------------
// Key insight: the A-fragment lane (lrow, lq) consumes for chunk kc — (row=lrow,
// rd-parity=lq>>1, ch-half=lq&1) — is EXACTLY one gather half-item. So each lane
// gathers its own 3 contributor 16B halves, combines in registers, and the packed
// bf16x8 feeds its MFMA directly. No zc intermediate (saves 184 MB of HBM), no LDS
// for A, no extra barriers.
//
// Software pipeline (full unroll, all slot indices kc&1 are compile-time):
//   iter kc: B-issue(kc+2) [oldest] -> combine(kc) [waits gathers issued kc-2]
//            -> gather-issue(kc+2) [uses meta issued kc-1] -> meta-issue(kc+3)
//            -> 8 ds_read B + 8 MFMA -> ds_write Bb (waits B issued kc-1, counted
//            wait leaves this iter's gathers/meta in flight).
// Center chunks 32..35: direct y16 load of (v_p, d) row half (no meta/combine).
__global__ __launch_bounds__(256) void fused_gather_gemm(const u16* __restrict__ y16,
                                                         const int* __restrict__ contrib,
                                                         const float* __restrict__ wbary,
                                                         const int* __restrict__ angles,
                                                         const u16* __restrict__ k2c,
                                                         const float* __restrict__ bias,
                                                         float* __restrict__ out) {
    __shared__ __align__(16) u16 Bb[2][128 * BSTR];   // 20,480 B
    const int t = threadIdx.x;
    const int w = t >> 6, lane = t & 63;
    const int lrow = lane & 15, lq = lane >> 4;
    const int s_p = lq >> 1;                 // rd parity this lane owns
    const int h8  = (lq & 1) * 8;            // ch-half element offset
    const int m0 = blockIdx.x * 64;
    const int arow = m0 + w * 16 + lrow;     // GEMM row == gather row (same lane!)
    const int b_p = (arow >= NV);
    const int v_p = arow - b_p * NV;
    const u16* __restrict__ yb = y16 + (size_t)b_p * NVD * CH + h8;  // batch table + half
    const int mb0 = v_p * 192 + s_p * 3;     // meta element base; idx(kc) = mb0 + kc*6
    const int sn = t >> 1, sh = (t & 1) * 16;

    // pipeline register sets (indices always compile-time under full unroll)
    u32x4 G[2][3];                 // gathered 16B halves (2-deep)
    int   mc[2][3], ma[2][3];      // meta: contributors, angles
    float mw[2][3], W[2][3];       // meta weights (loaded, pipelined copy)
    u32x4 bn[2][2];                // B-chunk staging regs (2-deep)

    f32x4 acc[8];
    #pragma unroll
    for (int nt = 0; nt < 8; ++nt) acc[nt] = (f32x4){0.f, 0.f, 0.f, 0.f};

#define META_ISSUE(KC) { const int P_ = (KC) & 1; const int o_ = mb0 + (KC) * 6;       \
    mc[P_][0] = contrib[o_]; mc[P_][1] = contrib[o_ + 1]; mc[P_][2] = contrib[o_ + 2]; \
    ma[P_][0] = angles[o_];  ma[P_][1] = angles[o_ + 1];  ma[P_][2] = angles[o_ + 2];  \
    mw[P_][0] = wbary[o_];   mw[P_][1] = wbary[o_ + 1];   mw[P_][2] = wbary[o_ + 2]; }

#define G_ISSUE(KC) { const int P_ = (KC) & 1;                                          \
    if ((KC) < 32) {                                                                    \
        _Pragma("unroll")                                                               \
        for (int j_ = 0; j_ < 3; ++j_) {                                                \
            G[P_][j_] = *(const u32x4*)(yb + (size_t)((unsigned)mc[P_][j_] * 128u +     \
                                                      (unsigned)ma[P_][j_] * 16u));     \
            W[P_][j_] = mw[P_][j_];                                                     \
        }                                                                               \
    } else {                                                                            \
        G[P_][0] = *(const u32x4*)(yb + (size_t)((unsigned)v_p * 128u +                 \
                                                 (unsigned)(2 * ((KC) - 32) + s_p) * 16u)); \
    } }

#define COMBINE(KC, A_) { const int P_ = (KC) & 1;                                      \
    if ((KC) < 32) {                                                                    \
        float ac_[8];                                                                   \
        _Pragma("unroll") for (int x_ = 0; x_ < 8; ++x_) ac_[x_] = 0.f;                 \
        _Pragma("unroll")                                                               \
        for (int j_ = 0; j_ < 3; ++j_) {                                                \
            float wj_ = W[P_][j_];                                                      \
            _Pragma("unroll")                                                           \
            for (int q_ = 0; q_ < 4; ++q_) {                                            \
                unsigned u_ = G[P_][j_][q_];                                            \
                ac_[2 * q_]     += wj_ * __uint_as_float(u_ << 16);                     \
                ac_[2 * q_ + 1] += wj_ * __uint_as_float(u_ & 0xffff0000u);             \
            }                                                                           \
        }                                                                               \
        u32x4 o_;                                                                       \
        _Pragma("unroll") for (int q_ = 0; q_ < 4; ++q_)                                \
            o_[q_] = pack2bf(ac_[2 * q_], ac_[2 * q_ + 1]);                             \
        A_ = *(bf16x8*)&o_;                                                             \
    } else { u32x4 o_ = G[P_][0]; A_ = *(bf16x8*)&o_; } }

    // ---- prologue ----
    META_ISSUE(0); META_ISSUE(1);
    {   // stage B(0) immediately
        const u32x4* src = (const u32x4*)(k2c + (size_t)0 * 4096 + sn * 32 + sh);
        u32x4 b0 = src[0], b1 = src[1];
        u16* dst = &Bb[0][sn * BSTR + sh];
        *(u32x4*)(dst)     = b0;
        *(u32x4*)(dst + 8) = b1;
    }
    G_ISSUE(0); META_ISSUE(2);    // meta(0) consumed -> slot 0 free for meta(2)
    G_ISSUE(1);                   // meta(1) consumed
    {   // B(1) -> bn[1] (consumed at iter 0's ds_write)
        const u32x4* src = (const u32x4*)(k2c + (size_t)1 * 4096 + sn * 32 + sh);
        bn[1][0] = src[0]; bn[1][1] = src[1];
    }

    // ---- main loop: 36 chunks, fully unrolled ----
    #pragma unroll
    for (int kc = 0; kc < NCHUNK; ++kc) {
        __syncthreads();                               // Bb[kc&1] visible
        if (kc + 2 < NCHUNK) {                         // B issue (oldest this iter)
            const u32x4* src = (const u32x4*)(k2c + (size_t)(kc + 2) * 4096 + sn * 32 + sh);
            bn[kc & 1][0] = src[0]; bn[kc & 1][1] = src[1];
        }
        bf16x8 a;
        COMBINE(kc, a);                                // waits gathers issued at kc-2
        if (kc + 2 < NCHUNK) G_ISSUE(kc + 2);          // uses meta issued at kc-1
        if (kc + 3 < 32)     META_ISSUE(kc + 3);
        bf16x8 bf[8];
        #pragma unroll
        for (int nt = 0; nt < 8; ++nt)
            bf[nt] = *(const bf16x8*)(&Bb[kc & 1][(nt * 16 + lrow) * BSTR + lq * 8]);
        #pragma unroll
        for (int nt = 0; nt < 8; ++nt)
            acc[nt] = __builtin_amdgcn_mfma_f32_16x16x32_bf16(a, bf[nt], acc[nt], 0, 0, 0);
        if (kc + 1 < NCHUNK) {                         // stage B(kc+1), loaded at kc-1
            u16* dst = &Bb[(kc + 1) & 1][sn * BSTR + sh];
            *(u32x4*)(dst)     = bn[(kc + 1) & 1][0];
            *(u32x4*)(dst + 8) = bn[(kc + 1) & 1][1];
        }
    }
#undef META_ISSUE
#undef G_ISSUE
#undef COMBINE

    // epilogue: +bias, relu, max over w (= max over nt), exclusive store
    const float bb = bias[lrow];
    #pragma unroll
    for (int reg = 0; reg < 4; ++reg) {
        float m = 0.f;   // relu floor
        #pragma unroll
        for (int nt = 0; nt < 8; ++nt) m = fmaxf(m, acc[nt][reg] + bb);
        out[((size_t)(m0 + w * 16 + lq * 4 + reg)) * NF + lrow] = m;
    }
}

extern "C" void kernel_launch(void* const* d_in, const int* in_sizes, int n_in,
                              void* d_out, int out_size, void* d_ws, size_t ws_size,
                              hipStream_t stream) {
    const float* y      = (const float*)d_in[0];
    const int*   contrib= (const int*)d_in[1];
    const float* wbary  = (const float*)d_in[2];
    const int*   angles = (const int*)d_in[3];
    const float* kern   = (const float*)d_in[4];
    const float* ck     = (const float*)d_in[5];
    const float* bias   = (const float*)d_in[6];
    float* out = (float*)d_out;

    u16* y16 = (u16*)((char*)d_ws + Y16_OFF_B);
    u16* k2c = (u16*)((char*)d_ws + K2C_OFF_B);

    prep<<<1250, 256, 0, stream>>>(y, y16);
    k2_build<<<(NCHUNK * 4096) / 256, 256, 0, stream>>>(kern, ck, k2c);
    fused_gather_gemm<<<MTOT / 64, 256, 0, stream>>>(y16, contrib, wbary, angles,
                                                     k2c, bias, out);
}

// Round 5
// 239.470 us; speedup vs baseline: 1.2500x; 1.2500x over previous
//
#include <hip/hip_runtime.h>

typedef unsigned short u16;
typedef __attribute__((ext_vector_type(4))) unsigned int u32x4;
typedef __attribute__((ext_vector_type(4))) float f32x4;
typedef __attribute__((ext_vector_type(8))) __bf16 bf16x8;

// Problem constants (fixed by the reference).
constexpr int BATCH = 2;
constexpr int NV    = 20000;
constexpr int ND    = 8;
constexpr int CH    = 16;
constexpr int NF    = 16;
constexpr int NVD   = NV * ND;        // 160000 rows of y_flat per batch
constexpr int NCHUNK = 36;            // 32 conv chunks + 4 center chunks (K=1152 total)
constexpr int MTOT  = BATCH * NV;     // 40000 GEMM rows
constexpr int BSTR  = 40;             // padded B row stride in bf16 (32+8)

// ws layout (bytes):
//   [0, 10,240,000)              y16  : bf16 [B][NVD][CH]
//   [10,240,000, 10,534,912)     k2c  : bf16 [36][128][32]  (chunk-major weights)
constexpr size_t Y16_OFF_B = 0;
constexpr size_t K2C_OFF_B = 10240000;

__device__ __forceinline__ u16 f2bf(float x) {
    unsigned int u = __float_as_uint(x);
    unsigned int r = (u + 0x7fffu + ((u >> 16) & 1u)) >> 16;   // RNE
    return (u16)r;
}
__device__ __forceinline__ unsigned int pack2bf(float a, float b) {
    return (unsigned int)f2bf(a) | ((unsigned int)f2bf(b) << 16);
}

// ---------------- P1: prep — y fp32 -> y16 bf16 table ----------------
__global__ __launch_bounds__(256) void prep(const float* __restrict__ y,
                                            u16* __restrict__ y16) {
    int tid = blockIdx.x * 256 + threadIdx.x;       // [0, 320000)
    const float4* src = (const float4*)(y + (size_t)tid * 16);
    float4 v0 = src[0], v1 = src[1], v2 = src[2], v3 = src[3];
    u32x4 lo = {pack2bf(v0.x, v0.y), pack2bf(v0.z, v0.w), pack2bf(v1.x, v1.y), pack2bf(v1.z, v1.w)};
    u32x4 hi = {pack2bf(v2.x, v2.y), pack2bf(v2.z, v2.w), pack2bf(v3.x, v3.y), pack2bf(v3.z, v3.w)};
    u16* yd = y16 + (size_t)tid * 16;
    *(u32x4*)(yd)     = lo;
    *(u32x4*)(yd + 8) = hi;
}

// ---------------- P2: build rotated+extended weight matrix K2c ----------------
__global__ __launch_bounds__(256) void k2_build(const float* __restrict__ kern,
                                                const float* __restrict__ ck,
                                                u16* __restrict__ k2c) {
    int e = blockIdx.x * 256 + threadIdx.x;   // [0, 36*4096)
    int i = e & 4095;
    int kc = e >> 12;
    int n = i >> 5, kk = i & 31;
    int k = kc * 32 + kk;
    int w = n >> 4, f = n & 15;
    float val;
    if (k < 1024) {
        int r = k >> 7, dd = (k >> 4) & 7, c = k & 15;
        int d = (dd - w) & 7;
        val = kern[((r * 8 + d) * 16 + c) * 16 + f];
    } else {
        int ke = k - 1024;
        int d = ke >> 4, c = ke & 15;
        val = (d == w) ? ck[c * 16 + f] : 0.f;
    }
    k2c[e] = f2bf(val);
}

// ---------------- F: FUSED gather + barycentric + GEMM + bias + relu + max ----------------
// r3 lesson (rule #20): the 2-deep pipeline state must live in NAMED registers, never
// in arrays indexed by a runtime parity. The loop is 18 iterations x {even,odd} phase;
// every slot is a distinct named variable, so all register accesses are compile-time.
// Schedule per chunk kc (phase): B-issue(kc+2) -> combine(kc) -> gather-issue(kc+2)
// -> meta-issue(kc+3) -> 8 ds_read + 8 MFMA -> ds_write B(kc+1).
// Center chunks 32..35: direct y16 row-half loads (no meta/combine).
__global__ __launch_bounds__(256) void fused_gather_gemm(const u16* __restrict__ y16,
                                                         const int* __restrict__ contrib,
                                                         const float* __restrict__ wbary,
                                                         const int* __restrict__ angles,
                                                         const u16* __restrict__ k2c,
                                                         const float* __restrict__ bias,
                                                         float* __restrict__ out) {
    __shared__ __align__(16) u16 Bb[2][128 * BSTR];   // 20,480 B
    const int t = threadIdx.x;
    const int w = t >> 6, lane = t & 63;
    const int lrow = lane & 15, lq = lane >> 4;
    const int s_p = lq >> 1;                 // rd parity this lane owns
    const int h8  = (lq & 1) * 8;            // ch-half element offset
    const int m0 = blockIdx.x * 64;
    const int arow = m0 + w * 16 + lrow;     // GEMM row == gather row (same lane!)
    const int b_p = (arow >= NV);
    const int v_p = arow - b_p * NV;
    const u16* __restrict__ yb = y16 + (size_t)b_p * NVD * CH + h8;  // batch table + half
    const int mb0 = v_p * 192 + s_p * 3;     // meta element base; idx(kc) = mb0 + kc*6
    const int sn = t >> 1, sh = (t & 1) * 16;

    // pipeline state — ALL named scalars/vectors (no runtime-indexed arrays)
    int   ce0, ce1, ce2, ae0, ae1, ae2;  float we0, we1, we2;   // meta, even chunks
    int   co0, co1, co2, ao0, ao1, ao2;  float wo0, wo1, wo2;   // meta, odd chunks
    u32x4 ge0, ge1, ge2;  float ve0, ve1, ve2;                  // gathers, even
    u32x4 go0, go1, go2;  float vo0, vo1, vo2;                  // gathers, odd
    u32x4 bne0, bne1, bno0, bno1;                               // B staging regs

    f32x4 acc[8];
    #pragma unroll
    for (int nt = 0; nt < 8; ++nt) acc[nt] = (f32x4){0.f, 0.f, 0.f, 0.f};

#define META_ISSUE(S, KC_) { const int o_ = mb0 + (KC_) * 6;                       \
    c##S##0 = contrib[o_]; c##S##1 = contrib[o_ + 1]; c##S##2 = contrib[o_ + 2];   \
    a##S##0 = angles[o_];  a##S##1 = angles[o_ + 1];  a##S##2 = angles[o_ + 2];    \
    w##S##0 = wbary[o_];   w##S##1 = wbary[o_ + 1];   w##S##2 = wbary[o_ + 2]; }

#define G_ISSUE(S, KC_) {                                                          \
    if ((KC_) < 32) {                                                              \
        g##S##0 = *(const u32x4*)(yb + (size_t)((unsigned)c##S##0 * 128u +         \
                                                (unsigned)a##S##0 * 16u));         \
        g##S##1 = *(const u32x4*)(yb + (size_t)((unsigned)c##S##1 * 128u +         \
                                                (unsigned)a##S##1 * 16u));         \
        g##S##2 = *(const u32x4*)(yb + (size_t)((unsigned)c##S##2 * 128u +         \
                                                (unsigned)a##S##2 * 16u));         \
        v##S##0 = w##S##0; v##S##1 = w##S##1; v##S##2 = w##S##2;                   \
    } else {                                                                       \
        g##S##0 = *(const u32x4*)(yb + (size_t)((unsigned)v_p * 128u +             \
                                      (unsigned)(2 * ((KC_) - 32) + s_p) * 16u));  \
    } }

#define COMBINE(S, KC_, A_) {                                                      \
    if ((KC_) < 32) {                                                              \
        float ac_[8];                                                              \
        _Pragma("unroll") for (int x_ = 0; x_ < 8; ++x_) ac_[x_] = 0.f;            \
        _Pragma("unroll")                                                          \
        for (int q_ = 0; q_ < 4; ++q_) {                                           \
            unsigned u0_ = g##S##0[q_], u1_ = g##S##1[q_], u2_ = g##S##2[q_];      \
            ac_[2 * q_]     += v##S##0 * __uint_as_float(u0_ << 16);               \
            ac_[2 * q_ + 1] += v##S##0 * __uint_as_float(u0_ & 0xffff0000u);       \
            ac_[2 * q_]     += v##S##1 * __uint_as_float(u1_ << 16);               \
            ac_[2 * q_ + 1] += v##S##1 * __uint_as_float(u1_ & 0xffff0000u);       \
            ac_[2 * q_]     += v##S##2 * __uint_as_float(u2_ << 16);               \
            ac_[2 * q_ + 1] += v##S##2 * __uint_as_float(u2_ & 0xffff0000u);       \
        }                                                                          \
        u32x4 o_;                                                                  \
        _Pragma("unroll") for (int q_ = 0; q_ < 4; ++q_)                           \
            o_[q_] = pack2bf(ac_[2 * q_], ac_[2 * q_ + 1]);                        \
        A_ = *(bf16x8*)&o_;                                                        \
    } else { u32x4 o_ = g##S##0; A_ = *(bf16x8*)&o_; } }

    // ---- prologue ----
    META_ISSUE(e, 0); META_ISSUE(o, 1);
    {   // stage B(0) directly
        const u32x4* src = (const u32x4*)(k2c + (size_t)0 * 4096 + sn * 32 + sh);
        u32x4 b0 = src[0], b1 = src[1];
        u16* dst = &Bb[0][sn * BSTR + sh];
        *(u32x4*)(dst)     = b0;
        *(u32x4*)(dst + 8) = b1;
    }
    G_ISSUE(e, 0); META_ISSUE(e, 2);     // meta(0) consumed -> even slot refilled with meta(2)
    G_ISSUE(o, 1);                       // meta(1) consumed
    {   // B(1) -> bno (consumed by iter p=0 even-phase ds_write)
        const u32x4* src = (const u32x4*)(k2c + (size_t)1 * 4096 + sn * 32 + sh);
        bno0 = src[0]; bno1 = src[1];
    }

    // ---- main loop: 18 pairs of chunks; all slot references compile-time ----
    for (int p = 0; p < 18; ++p) {
        const int k0 = 2 * p, k1 = 2 * p + 1;

        // ===== even chunk k0 =====
        __syncthreads();                                   // Bb[0] = B(k0) visible
        if (k0 + 2 < NCHUNK) {                             // B issue (oldest first)
            const u32x4* src = (const u32x4*)(k2c + (size_t)(k0 + 2) * 4096 + sn * 32 + sh);
            bne0 = src[0]; bne1 = src[1];
        }
        bf16x8 aev;
        COMBINE(e, k0, aev);                               // waits gathers issued at k0-2
        if (k0 + 2 < NCHUNK) G_ISSUE(e, k0 + 2);           // meta issued at k0-1
        if (k0 + 3 < 32)     META_ISSUE(o, k0 + 3);
        {
            bf16x8 bf[8];
            #pragma unroll
            for (int nt = 0; nt < 8; ++nt)
                bf[nt] = *(const bf16x8*)(&Bb[0][(nt * 16 + lrow) * BSTR + lq * 8]);
            #pragma unroll
            for (int nt = 0; nt < 8; ++nt)
                acc[nt] = __builtin_amdgcn_mfma_f32_16x16x32_bf16(aev, bf[nt], acc[nt], 0, 0, 0);
        }
        {   // stage B(k0+1) into Bb[1] (regs loaded at k0-1); k0+1 <= 35 always
            u16* dst = &Bb[1][sn * BSTR + sh];
            *(u32x4*)(dst)     = bno0;
            *(u32x4*)(dst + 8) = bno1;
        }

        // ===== odd chunk k1 =====
        __syncthreads();                                   // Bb[1] = B(k1) visible
        if (k1 + 2 < NCHUNK) {
            const u32x4* src = (const u32x4*)(k2c + (size_t)(k1 + 2) * 4096 + sn * 32 + sh);
            bno0 = src[0]; bno1 = src[1];
        }
        bf16x8 aov;
        COMBINE(o, k1, aov);
        if (k1 + 2 < NCHUNK) G_ISSUE(o, k1 + 2);
        if (k1 + 3 < 32)     META_ISSUE(e, k1 + 3);
        {
            bf16x8 bf[8];
            #pragma unroll
            for (int nt = 0; nt < 8; ++nt)
                bf[nt] = *(const bf16x8*)(&Bb[1][(nt * 16 + lrow) * BSTR + lq * 8]);
            #pragma unroll
            for (int nt = 0; nt < 8; ++nt)
                acc[nt] = __builtin_amdgcn_mfma_f32_16x16x32_bf16(aov, bf[nt], acc[nt], 0, 0, 0);
        }
        if (k1 + 1 < NCHUNK) {                             // stage B(k1+1) into Bb[0]
            u16* dst = &Bb[0][sn * BSTR + sh];
            *(u32x4*)(dst)     = bne0;
            *(u32x4*)(dst + 8) = bne1;
        }
    }
#undef META_ISSUE
#undef G_ISSUE
#undef COMBINE

    // epilogue: +bias, relu, max over w (= max over nt), exclusive store
    const float bb = bias[lrow];
    #pragma unroll
    for (int reg = 0; reg < 4; ++reg) {
        float m = 0.f;   // relu floor
        #pragma unroll
        for (int nt = 0; nt < 8; ++nt) m = fmaxf(m, acc[nt][reg] + bb);
        out[((size_t)(m0 + w * 16 + lq * 4 + reg)) * NF + lrow] = m;
    }
}

extern "C" void kernel_launch(void* const* d_in, const int* in_sizes, int n_in,
                              void* d_out, int out_size, void* d_ws, size_t ws_size,
                              hipStream_t stream) {
    const float* y      = (const float*)d_in[0];
    const int*   contrib= (const int*)d_in[1];
    const float* wbary  = (const float*)d_in[2];
    const int*   angles = (const int*)d_in[3];
    const float* kern   = (const float*)d_in[4];
    const float* ck     = (const float*)d_in[5];
    const float* bias   = (const float*)d_in[6];
    float* out = (float*)d_out;

    u16* y16 = (u16*)((char*)d_ws + Y16_OFF_B);
    u16* k2c = (u16*)((char*)d_ws + K2C_OFF_B);

    prep<<<1250, 256, 0, stream>>>(y, y16);
    k2_build<<<(NCHUNK * 4096) / 256, 256, 0, stream>>>(kern, ck, k2c);
    fused_gather_gemm<<<MTOT / 64, 256, 0, stream>>>(y16, contrib, wbary, angles,
                                                     k2c, bias, out);
}